// Round 2
// baseline (279.521 us; speedup 1.0000x reference)
//
#include <hip/hip_runtime.h>
#include <stdint.h>

#define BATCH    256
#define VOCAB    128000
#define HIST     200
#define TOPK     50
#define BITWORDS (VOCAB / 32)   // 4000 words = 16000 B

// --- two-kernel path parameters ---
#define SLICES   8              // blocks per row in the stream kernel
#define NT1      256            // threads, stream kernel
#define NT2      512            // threads, select kernel
#define LCAP     1024           // candidate capacity per row (expected ~173)
#define TRAW     3.0f           // pre-penalty threshold; P(N(0,1)>3)*128000 ~= 173

// --- monolithic fallback (original kernel) parameters ---
#define CAP      2048
#define NTHREADS 1024

typedef float f32x4_t __attribute__((ext_vector_type(4)));

// Monotonic float->uint key: descending float order == descending unsigned order.
__device__ __forceinline__ unsigned fkey_of(float f) {
  unsigned u = __float_as_uint(f);
  return (u & 0x80000000u) ? ~u : (u | 0x80000000u);
}
__device__ __forceinline__ float f_of_key(unsigned k) {
  unsigned u = (k & 0x80000000u) ? (k & 0x7FFFFFFFu) : ~k;
  return __uint_as_float(u);
}

__device__ __forceinline__ void push4(float4 v, unsigned v0,
                                      int* __restrict__ cnt,
                                      uint2* __restrict__ cand) {
  if (v.x > TRAW) { int p = atomicAdd(cnt, 1); if (p < LCAP) cand[p] = make_uint2(__float_as_uint(v.x), v0 + 0u); }
  if (v.y > TRAW) { int p = atomicAdd(cnt, 1); if (p < LCAP) cand[p] = make_uint2(__float_as_uint(v.y), v0 + 1u); }
  if (v.z > TRAW) { int p = atomicAdd(cnt, 1); if (p < LCAP) cand[p] = make_uint2(__float_as_uint(v.z), v0 + 2u); }
  if (v.w > TRAW) { int p = atomicAdd(cnt, 1); if (p < LCAP) cand[p] = make_uint2(__float_as_uint(v.w), v0 + 3u); }
}

// ============================================================================
// Kernel 1: pure streaming pass, unrolled x4 for memory-level parallelism.
// 2048 blocks (8 per row) x 256 threads. Read logits (4 float4 loads in
// flight), zero the output row (nontemporal), push raw candidates v > TRAW.
// Penalty applied later (it only shrinks values, so {y>T} subset of {v>T}).
// ============================================================================
__global__ __launch_bounds__(NT1) void stream_collect_kernel(
    const float* __restrict__ logits, float* __restrict__ out,
    int* __restrict__ cnt_g, uint2* __restrict__ cand_g)
{
  const int bid = blockIdx.x;
  const int b = bid >> 3;            // SLICES == 8
  const int s = bid & (SLICES - 1);
  const float4* row4  = (const float4*)(logits + (size_t)b * VOCAB);
  float4*       orow4 = (float4*)(out + (size_t)b * VOCAB);
  const int per = (VOCAB / 4) / SLICES;   // 4000 float4 per slice
  const int lo = s * per, hi = lo + per;
  int*   cnt  = cnt_g + b;
  uint2* cand = cand_g + (size_t)b * LCAP;

  const f32x4_t z4 = (f32x4_t)0.f;
  int i = lo + (int)threadIdx.x;

  // main loop: 4 independent loads in flight per wave
  for (; i + 3 * NT1 < hi; i += 4 * NT1) {
    float4 a = row4[i];
    float4 b4 = row4[i + NT1];
    float4 c = row4[i + 2 * NT1];
    float4 d = row4[i + 3 * NT1];
    __builtin_nontemporal_store(z4, (f32x4_t*)&orow4[i]);
    __builtin_nontemporal_store(z4, (f32x4_t*)&orow4[i + NT1]);
    __builtin_nontemporal_store(z4, (f32x4_t*)&orow4[i + 2 * NT1]);
    __builtin_nontemporal_store(z4, (f32x4_t*)&orow4[i + 3 * NT1]);
    push4(a, 4u * (unsigned)i, cnt, cand);
    push4(b4, 4u * (unsigned)(i + NT1), cnt, cand);
    push4(c, 4u * (unsigned)(i + 2 * NT1), cnt, cand);
    push4(d, 4u * (unsigned)(i + 3 * NT1), cnt, cand);
  }
  // tail
  for (; i < hi; i += NT1) {
    float4 a = row4[i];
    __builtin_nontemporal_store(z4, (f32x4_t*)&orow4[i]);
    push4(a, 4u * (unsigned)i, cnt, cand);
  }
}

// ============================================================================
// Kernel 2: per-row selection. 256 blocks x 512 threads. Penalty + temperature
// on ~173 candidates, rank sort (keys unique via idx tie-break -> bijection),
// top-k boundary w/ ties, nucleus cutoff, scatter.
// Self-contained bisection rescan fallback if the candidate set is invalid
// (never for this input distribution).
// ============================================================================
__global__ __launch_bounds__(NT2) void select_kernel(
    const float* __restrict__ logits, const int* __restrict__ prev,
    float* __restrict__ out, const int* __restrict__ cnt_g,
    const uint2* __restrict__ cand_g)
{
  __shared__ unsigned bitmask[BITWORDS];          // 16000 B
  __shared__ unsigned long long keys[LCAP];       //  8192 B
  __shared__ unsigned long long skeys[LCAP];      //  8192 B
  __shared__ float evals[LCAP];                   //  4096 B
  __shared__ int s_cnt, s_good, s_m, s_j;
  __shared__ float s_maxx, s_Z2;

  const int b   = blockIdx.x;
  const int tid = threadIdx.x;
  const float* row  = logits + (size_t)b * VOCAB;
  float*       orow = out    + (size_t)b * VOCAB;

  // ---- seen-token bitmask ----
  for (int i = tid; i < BITWORDS; i += NT2) bitmask[i] = 0u;
  if (tid == 0) s_good = 0;
  __syncthreads();
  for (int i = tid; i < HIST; i += NT2) {
    int t = prev[b * HIST + i];
    atomicOr(&bitmask[t >> 5], 1u << (t & 31));
  }
  __syncthreads();

  // ---- fast path: penalize + temperature the collected candidates ----
  int cnt = cnt_g[b];
  int mn = cnt < LCAP ? cnt : LCAP;
  const uint2* cand = cand_g + (size_t)b * LCAP;
  for (int i = tid; i < mn; i += NT2) {
    uint2 c = cand[i];
    float v = __uint_as_float(c.x);
    unsigned idx = c.y;
    float y = v;
    if ((bitmask[idx >> 5] >> (idx & 31)) & 1u)
      y = (v < 0.0f) ? v * 1.2f : v / 1.2f;        // repetition penalty
    float x = y / 0.6f;                            // temperature (exact IEEE div)
    keys[i] = ((unsigned long long)fkey_of(x) << 32) |
              (unsigned)(~idx);                    // tie-break: smaller idx first
    if (y > TRAW) atomicAdd(&s_good, 1);
  }
  __syncthreads();

  // Valid iff all tokens with y > TRAW were collected AND >= TOPK of them exist
  // (tokens not collected have y <= TRAW, so kth_y > TRAW guarantees coverage).
  if (cnt > LCAP || s_good < TOPK) {
    // ---- fallback: bisection rescan from global memory (rare/never) ----
    float T = TRAW;
    float Tlo = 0.f, Thi = 0.f;
    bool hasLo = false, hasHi = false;
    const float4* row4 = (const float4*)row;
    const int N4 = VOCAB / 4;
    for (int attempt = 0; attempt < 40; ++attempt) {
      __syncthreads();
      if (tid == 0) s_cnt = 0;
      __syncthreads();
      for (int i = tid; i < N4; i += NT2) {
        float4 v4 = row4[i];
        int v0 = i * 4;
        unsigned w  = bitmask[v0 >> 5];
        unsigned sh = v0 & 31;
        float vv[4] = {v4.x, v4.y, v4.z, v4.w};
        #pragma unroll
        for (int l = 0; l < 4; ++l) {
          float v = vv[l];
          float y = v;
          if ((w >> (sh + l)) & 1u)
            y = (v < 0.0f) ? v * 1.2f : v / 1.2f;
          if (y > T) {
            int pos = atomicAdd(&s_cnt, 1);
            if (pos < LCAP) {
              unsigned k = fkey_of(y / 0.6f);
              keys[pos] = ((unsigned long long)k << 32) |
                          (unsigned)(~(unsigned)(v0 + l));
            }
          }
        }
      }
      __syncthreads();
      cnt = s_cnt;
      if (cnt >= TOPK && cnt <= LCAP) break;
      if (cnt < TOPK) { Thi = T; hasHi = true; T = hasLo ? 0.5f * (T + Tlo) : T - 1.0f; }
      else            { Tlo = T; hasLo = true; T = hasHi ? 0.5f * (T + Thi) : T + 1.0f; }
    }
    if (cnt > LCAP) cnt = LCAP;
  }

  // ---- rank sort: keys unique (idx tie-break) => ranks are a bijection ----
  // cnt ~173: each thread ranks <=1 key with an LDS-broadcast inner loop.
  for (int i = tid; i < cnt; i += NT2) {
    unsigned long long a = keys[i];
    int r = 0;
    for (int j = 0; j < cnt; ++j) r += (keys[j] > a);
    skeys[r] = a;
  }
  __syncthreads();

  // ---- top-k boundary (keep ties at kth) + max ----
  if (tid == 0) {
    int kk = (cnt < TOPK) ? cnt : TOPK;
    unsigned kth = (unsigned)(skeys[kk - 1] >> 32);
    int m = kk;
    while (m < cnt && (unsigned)(skeys[m] >> 32) == kth) m++;
    s_m = m;
    s_maxx = f_of_key((unsigned)(skeys[0] >> 32));
  }
  __syncthreads();
  int m = s_m;
  float maxx = s_maxx;
  for (int i = tid; i < m; i += NT2)
    evals[i] = expf(f_of_key((unsigned)(skeys[i] >> 32)) - maxx);
  __syncthreads();

  // ---- nucleus cutoff: keep token i iff i==0 or cumsum(p[0..i-1]) <= 0.9 ----
  if (tid == 0) {
    float Z = 0.f;
    for (int i = 0; i < m; ++i) Z += evals[i];
    float cum = 0.f;
    int j = 0;
    for (int i = 0; i < m; ++i) {
      if (i > 0 && cum > 0.9f) break;
      cum += evals[i] / Z;
      j = i + 1;
    }
    float Z2 = 0.f;
    for (int i = 0; i < j; ++i) Z2 += evals[i];
    s_j = j; s_Z2 = Z2;
  }
  __syncthreads();

  // ---- scatter final probs (row already zeroed by kernel 1) ----
  int j = s_j;
  float Z2 = s_Z2;
  for (int i = tid; i < j; i += NT2) {
    int idx = (int)(~(unsigned)(skeys[i] & 0xFFFFFFFFull));
    orow[idx] = evals[i] / Z2;
  }
}

// ============================================================================
// Monolithic fallback (previous best kernel) — used only if ws_size is too
// small for the two-kernel workspace.
// ============================================================================
__global__ __launch_bounds__(NTHREADS) void sample_head_kernel(
    const float* __restrict__ logits, const int* __restrict__ prev,
    float* __restrict__ out)
{
  __shared__ unsigned bitmask[BITWORDS];
  __shared__ unsigned long long keys[CAP];
  __shared__ float evals[CAP];
  __shared__ int s_count;
  __shared__ int s_m, s_j;
  __shared__ float s_maxx, s_Z2;

  const int b   = blockIdx.x;
  const int tid = threadIdx.x;
  const float* row  = logits + (size_t)b * VOCAB;
  float*       orow = out    + (size_t)b * VOCAB;

  for (int i = tid; i < BITWORDS; i += NTHREADS) bitmask[i] = 0u;
  __syncthreads();
  for (int i = tid; i < HIST; i += NTHREADS) {
    int t = prev[b * HIST + i];
    atomicOr(&bitmask[t >> 5], 1u << (t & 31));
  }
  __syncthreads();

  float T = 3.0f;
  float Tlo = 0.f, Thi = 0.f;
  bool hasLo = false, hasHi = false;
  int cnt = 0;

  const float4* row4  = (const float4*)row;
  float4*       orow4 = (float4*)orow;
  const int N4 = VOCAB / 4;

  for (int attempt = 0; attempt < 40; ++attempt) {
    __syncthreads();
    if (tid == 0) s_count = 0;
    __syncthreads();

    for (int i = tid; i < N4; i += NTHREADS) {
      float4 v4 = row4[i];
      if (attempt == 0) orow4[i] = make_float4(0.f, 0.f, 0.f, 0.f);
      int v0 = i * 4;
      unsigned w  = bitmask[v0 >> 5];
      unsigned sh = v0 & 31;
      float vv[4] = {v4.x, v4.y, v4.z, v4.w};
      #pragma unroll
      for (int l = 0; l < 4; ++l) {
        float v = vv[l];
        float y = v;
        if ((w >> (sh + l)) & 1u)
          y = (v < 0.0f) ? v * 1.2f : v / 1.2f;
        if (y > T) {
          float x = y / 0.6f;
          int pos = atomicAdd(&s_count, 1);
          if (pos < CAP) {
            unsigned k = fkey_of(x);
            keys[pos] = ((unsigned long long)k << 32) |
                        (unsigned)(~(unsigned)(v0 + l));
          }
        }
      }
    }
    __syncthreads();
    cnt = s_count;
    if (cnt >= TOPK && cnt <= CAP) break;
    if (cnt < TOPK) { Thi = T; hasHi = true; T = hasLo ? 0.5f * (T + Tlo) : T - 1.0f; }
    else            { Tlo = T; hasLo = true; T = hasHi ? 0.5f * (T + Thi) : T + 1.0f; }
  }
  if (cnt > CAP) cnt = CAP;

  int n = 64;
  while (n < cnt) n <<= 1;
  for (int i = cnt + tid; i < n; i += NTHREADS) keys[i] = 0ull;
  __syncthreads();
  for (int k = 2; k <= n; k <<= 1) {
    for (int j = k >> 1; j > 0; j >>= 1) {
      for (int i = tid; i < n; i += NTHREADS) {
        int l = i ^ j;
        if (l > i) {
          unsigned long long a = keys[i], c = keys[l];
          bool up = (i & k) == 0;
          if (up ? (a < c) : (a > c)) { keys[i] = c; keys[l] = a; }
        }
      }
      __syncthreads();
    }
  }

  if (tid == 0) {
    int kk = (cnt < TOPK) ? cnt : TOPK;
    unsigned kth = (unsigned)(keys[kk - 1] >> 32);
    int m = kk;
    while (m < cnt && (unsigned)(keys[m] >> 32) == kth) m++;
    s_m = m;
    s_maxx = f_of_key((unsigned)(keys[0] >> 32));
  }
  __syncthreads();
  int m = s_m;
  float maxx = s_maxx;
  for (int i = tid; i < m; i += NTHREADS)
    evals[i] = expf(f_of_key((unsigned)(keys[i] >> 32)) - maxx);
  __syncthreads();

  if (tid == 0) {
    float Z = 0.f;
    for (int i = 0; i < m; ++i) Z += evals[i];
    float cum = 0.f;
    int j = 0;
    for (int i = 0; i < m; ++i) {
      if (i > 0 && cum > 0.9f) break;
      cum += evals[i] / Z;
      j = i + 1;
    }
    float Z2 = 0.f;
    for (int i = 0; i < j; ++i) Z2 += evals[i];
    s_j = j; s_Z2 = Z2;
  }
  __syncthreads();

  int j = s_j;
  float Z2 = s_Z2;
  for (int i = tid; i < j; i += NTHREADS) {
    int idx = (int)(~(unsigned)(keys[i] & 0xFFFFFFFFull));
    orow[idx] = evals[i] / Z2;
  }
}

extern "C" void kernel_launch(void* const* d_in, const int* in_sizes, int n_in,
                              void* d_out, int out_size, void* d_ws, size_t ws_size,
                              hipStream_t stream) {
  const float* logits = (const float*)d_in[0];
  const int*   prev   = (const int*)d_in[1];
  float*       out    = (float*)d_out;

  const size_t cnt_bytes  = (size_t)BATCH * sizeof(int);
  const size_t cand_off   = 1024;  // 8B-aligned, past counters
  const size_t need       = cand_off + (size_t)BATCH * LCAP * sizeof(uint2);

  if (d_ws != nullptr && ws_size >= need) {
    int*   cnt_g  = (int*)d_ws;
    uint2* cand_g = (uint2*)((char*)d_ws + cand_off);
    hipMemsetAsync(d_ws, 0, cnt_bytes, stream);
    hipLaunchKernelGGL(stream_collect_kernel, dim3(BATCH * SLICES), dim3(NT1),
                       0, stream, logits, out, cnt_g, cand_g);
    hipLaunchKernelGGL(select_kernel, dim3(BATCH), dim3(NT2),
                       0, stream, logits, prev, out, cnt_g, cand_g);
  } else {
    hipLaunchKernelGGL(sample_head_kernel, dim3(BATCH), dim3(NTHREADS),
                       0, stream, logits, prev, out);
  }
}

// Round 3
// 260.599 us; speedup vs baseline: 1.0726x; 1.0726x over previous
//
#include <hip/hip_runtime.h>
#include <stdint.h>

#define BATCH    256
#define VOCAB    128000
#define HIST     200
#define TOPK     50
#define BITWORDS (VOCAB / 32)   // 4000 words = 16000 B

// --- two-kernel path parameters ---
#define SLICES   8              // blocks per row in the collect kernel
#define NT1      256            // threads, collect kernel
#define NT2      512            // threads, select kernel
#define LCAP     1024           // candidate capacity per row (expected ~173)
#define TRAW     3.0f           // pre-penalty threshold; P(N(0,1)>3)*128000 ~= 173

// --- monolithic fallback (original kernel) parameters ---
#define CAP      2048
#define NTHREADS 1024

// Monotonic float->uint key: descending float order == descending unsigned order.
__device__ __forceinline__ unsigned fkey_of(float f) {
  unsigned u = __float_as_uint(f);
  return (u & 0x80000000u) ? ~u : (u | 0x80000000u);
}
__device__ __forceinline__ float f_of_key(unsigned k) {
  unsigned u = (k & 0x80000000u) ? (k & 0x7FFFFFFFu) : ~k;
  return __uint_as_float(u);
}

__device__ __forceinline__ void push4(float4 v, unsigned v0,
                                      int* __restrict__ cnt,
                                      uint2* __restrict__ cand) {
  if (v.x > TRAW) { int p = atomicAdd(cnt, 1); if (p < LCAP) cand[p] = make_uint2(__float_as_uint(v.x), v0 + 0u); }
  if (v.y > TRAW) { int p = atomicAdd(cnt, 1); if (p < LCAP) cand[p] = make_uint2(__float_as_uint(v.y), v0 + 1u); }
  if (v.z > TRAW) { int p = atomicAdd(cnt, 1); if (p < LCAP) cand[p] = make_uint2(__float_as_uint(v.z), v0 + 2u); }
  if (v.w > TRAW) { int p = atomicAdd(cnt, 1); if (p < LCAP) cand[p] = make_uint2(__float_as_uint(v.w), v0 + 3u); }
}

__device__ __forceinline__ float max4(float4 v) {
  return fmaxf(fmaxf(v.x, v.y), fmaxf(v.z, v.w));
}

// ============================================================================
// Kernel 1: READ-ONLY collect. 2048 blocks (8 per row) x 256 threads.
// No stores in the loop (output zeroing moved to hipMemsetAsync), so the
// vmcnt FIFO holds only reads -> real 4-deep MLP. Rare-push gated by a single
// fmax-reduce branch per float4 (p ~ 0.5%).
// Penalty applied later (it only shrinks values, so {y>T} subset of {v>T}).
// ============================================================================
__global__ __launch_bounds__(NT1) void collect_kernel(
    const float* __restrict__ logits,
    int* __restrict__ cnt_g, uint2* __restrict__ cand_g)
{
  const int bid = blockIdx.x;
  const int b = bid >> 3;            // SLICES == 8
  const int s = bid & (SLICES - 1);
  const float4* row4 = (const float4*)(logits + (size_t)b * VOCAB);
  const int per = (VOCAB / 4) / SLICES;   // 4000 float4 per slice
  const int lo = s * per, hi = lo + per;
  int*   cnt  = cnt_g + b;
  uint2* cand = cand_g + (size_t)b * LCAP;

  int i = lo + (int)threadIdx.x;

  // main loop: 4 independent loads issued before any consume
  for (; i + 3 * NT1 < hi; i += 4 * NT1) {
    float4 a = row4[i];
    float4 b4 = row4[i + NT1];
    float4 c = row4[i + 2 * NT1];
    float4 d = row4[i + 3 * NT1];
    if (max4(a)  > TRAW) push4(a,  4u * (unsigned)i,             cnt, cand);
    if (max4(b4) > TRAW) push4(b4, 4u * (unsigned)(i + NT1),     cnt, cand);
    if (max4(c)  > TRAW) push4(c,  4u * (unsigned)(i + 2 * NT1), cnt, cand);
    if (max4(d)  > TRAW) push4(d,  4u * (unsigned)(i + 3 * NT1), cnt, cand);
  }
  // tail
  for (; i < hi; i += NT1) {
    float4 a = row4[i];
    if (max4(a) > TRAW) push4(a, 4u * (unsigned)i, cnt, cand);
  }
}

// ============================================================================
// Kernel 2: per-row selection. 256 blocks x 512 threads. Penalty + temperature
// on ~173 candidates, rank sort (keys unique via idx tie-break -> bijection),
// top-k boundary w/ ties, nucleus cutoff, scatter.
// Self-contained bisection rescan fallback if the candidate set is invalid
// (never for this input distribution).
// ============================================================================
__global__ __launch_bounds__(NT2) void select_kernel(
    const float* __restrict__ logits, const int* __restrict__ prev,
    float* __restrict__ out, const int* __restrict__ cnt_g,
    const uint2* __restrict__ cand_g)
{
  __shared__ unsigned bitmask[BITWORDS];          // 16000 B
  __shared__ unsigned long long keys[LCAP];       //  8192 B
  __shared__ unsigned long long skeys[LCAP];      //  8192 B
  __shared__ float evals[LCAP];                   //  4096 B
  __shared__ int s_cnt, s_good, s_m, s_j;
  __shared__ float s_maxx, s_Z2;

  const int b   = blockIdx.x;
  const int tid = threadIdx.x;
  const float* row  = logits + (size_t)b * VOCAB;
  float*       orow = out    + (size_t)b * VOCAB;

  // ---- seen-token bitmask ----
  for (int i = tid; i < BITWORDS; i += NT2) bitmask[i] = 0u;
  if (tid == 0) s_good = 0;
  __syncthreads();
  for (int i = tid; i < HIST; i += NT2) {
    int t = prev[b * HIST + i];
    atomicOr(&bitmask[t >> 5], 1u << (t & 31));
  }
  __syncthreads();

  // ---- fast path: penalize + temperature the collected candidates ----
  int cnt = cnt_g[b];
  int mn = cnt < LCAP ? cnt : LCAP;
  const uint2* cand = cand_g + (size_t)b * LCAP;
  for (int i = tid; i < mn; i += NT2) {
    uint2 c = cand[i];
    float v = __uint_as_float(c.x);
    unsigned idx = c.y;
    float y = v;
    if ((bitmask[idx >> 5] >> (idx & 31)) & 1u)
      y = (v < 0.0f) ? v * 1.2f : v / 1.2f;        // repetition penalty
    float x = y / 0.6f;                            // temperature (exact IEEE div)
    keys[i] = ((unsigned long long)fkey_of(x) << 32) |
              (unsigned)(~idx);                    // tie-break: smaller idx first
    if (y > TRAW) atomicAdd(&s_good, 1);
  }
  __syncthreads();

  // Valid iff all tokens with y > TRAW were collected AND >= TOPK of them exist
  // (tokens not collected have y <= TRAW, so kth_y > TRAW guarantees coverage).
  if (cnt > LCAP || s_good < TOPK) {
    // ---- fallback: bisection rescan from global memory (rare/never) ----
    float T = TRAW;
    float Tlo = 0.f, Thi = 0.f;
    bool hasLo = false, hasHi = false;
    const float4* row4 = (const float4*)row;
    const int N4 = VOCAB / 4;
    for (int attempt = 0; attempt < 40; ++attempt) {
      __syncthreads();
      if (tid == 0) s_cnt = 0;
      __syncthreads();
      for (int i = tid; i < N4; i += NT2) {
        float4 v4 = row4[i];
        int v0 = i * 4;
        unsigned w  = bitmask[v0 >> 5];
        unsigned sh = v0 & 31;
        float vv[4] = {v4.x, v4.y, v4.z, v4.w};
        #pragma unroll
        for (int l = 0; l < 4; ++l) {
          float v = vv[l];
          float y = v;
          if ((w >> (sh + l)) & 1u)
            y = (v < 0.0f) ? v * 1.2f : v / 1.2f;
          if (y > T) {
            int pos = atomicAdd(&s_cnt, 1);
            if (pos < LCAP) {
              unsigned k = fkey_of(y / 0.6f);
              keys[pos] = ((unsigned long long)k << 32) |
                          (unsigned)(~(unsigned)(v0 + l));
            }
          }
        }
      }
      __syncthreads();
      cnt = s_cnt;
      if (cnt >= TOPK && cnt <= LCAP) break;
      if (cnt < TOPK) { Thi = T; hasHi = true; T = hasLo ? 0.5f * (T + Tlo) : T - 1.0f; }
      else            { Tlo = T; hasLo = true; T = hasHi ? 0.5f * (T + Thi) : T + 1.0f; }
    }
    if (cnt > LCAP) cnt = LCAP;
  }

  // ---- rank sort: keys unique (idx tie-break) => ranks are a bijection ----
  // cnt ~173: each thread ranks <=1 key with an LDS-broadcast inner loop.
  for (int i = tid; i < cnt; i += NT2) {
    unsigned long long a = keys[i];
    int r = 0;
    for (int j = 0; j < cnt; ++j) r += (keys[j] > a);
    skeys[r] = a;
  }
  __syncthreads();

  // ---- top-k boundary (keep ties at kth) + max ----
  if (tid == 0) {
    int kk = (cnt < TOPK) ? cnt : TOPK;
    unsigned kth = (unsigned)(skeys[kk - 1] >> 32);
    int m = kk;
    while (m < cnt && (unsigned)(skeys[m] >> 32) == kth) m++;
    s_m = m;
    s_maxx = f_of_key((unsigned)(skeys[0] >> 32));
  }
  __syncthreads();
  int m = s_m;
  float maxx = s_maxx;
  for (int i = tid; i < m; i += NT2)
    evals[i] = expf(f_of_key((unsigned)(skeys[i] >> 32)) - maxx);
  __syncthreads();

  // ---- nucleus cutoff: keep token i iff i==0 or cumsum(p[0..i-1]) <= 0.9 ----
  if (tid == 0) {
    float Z = 0.f;
    for (int i = 0; i < m; ++i) Z += evals[i];
    float cum = 0.f;
    int j = 0;
    for (int i = 0; i < m; ++i) {
      if (i > 0 && cum > 0.9f) break;
      cum += evals[i] / Z;
      j = i + 1;
    }
    float Z2 = 0.f;
    for (int i = 0; i < j; ++i) Z2 += evals[i];
    s_j = j; s_Z2 = Z2;
  }
  __syncthreads();

  // ---- scatter final probs (row already zeroed by memset) ----
  int j = s_j;
  float Z2 = s_Z2;
  for (int i = tid; i < j; i += NT2) {
    int idx = (int)(~(unsigned)(skeys[i] & 0xFFFFFFFFull));
    orow[idx] = evals[i] / Z2;
  }
}

// ============================================================================
// Monolithic fallback (round-0 kernel) — used only if ws_size is too small
// for the two-kernel workspace.
// ============================================================================
__global__ __launch_bounds__(NTHREADS) void sample_head_kernel(
    const float* __restrict__ logits, const int* __restrict__ prev,
    float* __restrict__ out)
{
  __shared__ unsigned bitmask[BITWORDS];
  __shared__ unsigned long long keys[CAP];
  __shared__ float evals[CAP];
  __shared__ int s_count;
  __shared__ int s_m, s_j;
  __shared__ float s_maxx, s_Z2;

  const int b   = blockIdx.x;
  const int tid = threadIdx.x;
  const float* row  = logits + (size_t)b * VOCAB;
  float*       orow = out    + (size_t)b * VOCAB;

  for (int i = tid; i < BITWORDS; i += NTHREADS) bitmask[i] = 0u;
  __syncthreads();
  for (int i = tid; i < HIST; i += NTHREADS) {
    int t = prev[b * HIST + i];
    atomicOr(&bitmask[t >> 5], 1u << (t & 31));
  }
  __syncthreads();

  float T = 3.0f;
  float Tlo = 0.f, Thi = 0.f;
  bool hasLo = false, hasHi = false;
  int cnt = 0;

  const float4* row4  = (const float4*)row;
  float4*       orow4 = (float4*)orow;
  const int N4 = VOCAB / 4;

  for (int attempt = 0; attempt < 40; ++attempt) {
    __syncthreads();
    if (tid == 0) s_count = 0;
    __syncthreads();

    for (int i = tid; i < N4; i += NTHREADS) {
      float4 v4 = row4[i];
      if (attempt == 0) orow4[i] = make_float4(0.f, 0.f, 0.f, 0.f);
      int v0 = i * 4;
      unsigned w  = bitmask[v0 >> 5];
      unsigned sh = v0 & 31;
      float vv[4] = {v4.x, v4.y, v4.z, v4.w};
      #pragma unroll
      for (int l = 0; l < 4; ++l) {
        float v = vv[l];
        float y = v;
        if ((w >> (sh + l)) & 1u)
          y = (v < 0.0f) ? v * 1.2f : v / 1.2f;
        if (y > T) {
          float x = y / 0.6f;
          int pos = atomicAdd(&s_count, 1);
          if (pos < CAP) {
            unsigned k = fkey_of(x);
            keys[pos] = ((unsigned long long)k << 32) |
                        (unsigned)(~(unsigned)(v0 + l));
          }
        }
      }
    }
    __syncthreads();
    cnt = s_count;
    if (cnt >= TOPK && cnt <= CAP) break;
    if (cnt < TOPK) { Thi = T; hasHi = true; T = hasLo ? 0.5f * (T + Tlo) : T - 1.0f; }
    else            { Tlo = T; hasLo = true; T = hasHi ? 0.5f * (T + Thi) : T + 1.0f; }
  }
  if (cnt > CAP) cnt = CAP;

  int n = 64;
  while (n < cnt) n <<= 1;
  for (int i = cnt + tid; i < n; i += NTHREADS) keys[i] = 0ull;
  __syncthreads();
  for (int k = 2; k <= n; k <<= 1) {
    for (int j = k >> 1; j > 0; j >>= 1) {
      for (int i = tid; i < n; i += NTHREADS) {
        int l = i ^ j;
        if (l > i) {
          unsigned long long a = keys[i], c = keys[l];
          bool up = (i & k) == 0;
          if (up ? (a < c) : (a > c)) { keys[i] = c; keys[l] = a; }
        }
      }
      __syncthreads();
    }
  }

  if (tid == 0) {
    int kk = (cnt < TOPK) ? cnt : TOPK;
    unsigned kth = (unsigned)(keys[kk - 1] >> 32);
    int m = kk;
    while (m < cnt && (unsigned)(keys[m] >> 32) == kth) m++;
    s_m = m;
    s_maxx = f_of_key((unsigned)(keys[0] >> 32));
  }
  __syncthreads();
  int m = s_m;
  float maxx = s_maxx;
  for (int i = tid; i < m; i += NTHREADS)
    evals[i] = expf(f_of_key((unsigned)(keys[i] >> 32)) - maxx);
  __syncthreads();

  if (tid == 0) {
    float Z = 0.f;
    for (int i = 0; i < m; ++i) Z += evals[i];
    float cum = 0.f;
    int j = 0;
    for (int i = 0; i < m; ++i) {
      if (i > 0 && cum > 0.9f) break;
      cum += evals[i] / Z;
      j = i + 1;
    }
    float Z2 = 0.f;
    for (int i = 0; i < j; ++i) Z2 += evals[i];
    s_j = j; s_Z2 = Z2;
  }
  __syncthreads();

  int j = s_j;
  float Z2 = s_Z2;
  for (int i = tid; i < j; i += NTHREADS) {
    int idx = (int)(~(unsigned)(keys[i] & 0xFFFFFFFFull));
    orow[idx] = evals[i] / Z2;
  }
}

extern "C" void kernel_launch(void* const* d_in, const int* in_sizes, int n_in,
                              void* d_out, int out_size, void* d_ws, size_t ws_size,
                              hipStream_t stream) {
  const float* logits = (const float*)d_in[0];
  const int*   prev   = (const int*)d_in[1];
  float*       out    = (float*)d_out;

  const size_t cnt_bytes  = (size_t)BATCH * sizeof(int);
  const size_t cand_off   = 1024;  // 8B-aligned, past counters
  const size_t need       = cand_off + (size_t)BATCH * LCAP * sizeof(uint2);
  const size_t out_bytes  = (size_t)BATCH * VOCAB * sizeof(float);

  if (d_ws != nullptr && ws_size >= need) {
    int*   cnt_g  = (int*)d_ws;
    uint2* cand_g = (uint2*)((char*)d_ws + cand_off);
    hipMemsetAsync(d_ws, 0, cnt_bytes, stream);
    hipLaunchKernelGGL(collect_kernel, dim3(BATCH * SLICES), dim3(NT1),
                       0, stream, logits, cnt_g, cand_g);
    // Pure write stream, decoupled from the read kernel above.
    hipMemsetAsync(out, 0, out_bytes, stream);
    hipLaunchKernelGGL(select_kernel, dim3(BATCH), dim3(NT2),
                       0, stream, logits, prev, out, cnt_g, cand_g);
  } else {
    hipLaunchKernelGGL(sample_head_kernel, dim3(BATCH), dim3(NTHREADS),
                       0, stream, logits, prev, out);
  }
}

// Round 4
// 255.603 us; speedup vs baseline: 1.0936x; 1.0195x over previous
//
#include <hip/hip_runtime.h>
#include <stdint.h>

#define BATCH    256
#define VOCAB    128000
#define HIST     200
#define TOPK     50
#define BITWORDS (VOCAB / 32)   // 4000 words = 16000 B

// --- two-kernel path parameters ---
#define SLICES   8              // collect blocks per row
#define CBLK     (BATCH * SLICES)   // 2048 collect blocks
#define ZBLK     2048               // zeroing blocks
#define NT1      256            // threads, collect/zero kernel
#define NT2      512            // threads, select kernel
#define LCAP     1024           // candidate capacity per row (expected ~173)
#define TRAW     3.0f           // pre-penalty threshold; P(N(0,1)>3)*128000 ~= 173

// --- monolithic fallback (original kernel) parameters ---
#define CAP      2048
#define NTHREADS 1024

typedef float f32x4_t __attribute__((ext_vector_type(4)));

// Monotonic float->uint key: descending float order == descending unsigned order.
__device__ __forceinline__ unsigned fkey_of(float f) {
  unsigned u = __float_as_uint(f);
  return (u & 0x80000000u) ? ~u : (u | 0x80000000u);
}
__device__ __forceinline__ float f_of_key(unsigned k) {
  unsigned u = (k & 0x80000000u) ? (k & 0x7FFFFFFFu) : ~k;
  return __uint_as_float(u);
}

__device__ __forceinline__ void push4(float4 v, unsigned v0,
                                      int* __restrict__ cnt,
                                      uint2* __restrict__ cand) {
  if (v.x > TRAW) { int p = atomicAdd(cnt, 1); if (p < LCAP) cand[p] = make_uint2(__float_as_uint(v.x), v0 + 0u); }
  if (v.y > TRAW) { int p = atomicAdd(cnt, 1); if (p < LCAP) cand[p] = make_uint2(__float_as_uint(v.y), v0 + 1u); }
  if (v.z > TRAW) { int p = atomicAdd(cnt, 1); if (p < LCAP) cand[p] = make_uint2(__float_as_uint(v.z), v0 + 2u); }
  if (v.w > TRAW) { int p = atomicAdd(cnt, 1); if (p < LCAP) cand[p] = make_uint2(__float_as_uint(v.w), v0 + 3u); }
}

__device__ __forceinline__ float max4(float4 v) {
  return fmaxf(fmaxf(v.x, v.y), fmaxf(v.z, v.w));
}

// ============================================================================
// Kernel 1: block-specialized collect + zero.
//  - blocks [0, CBLK):      READ-ONLY candidate collect (proven fast path:
//                           only loads in the wave's vmcnt FIFO -> 4-deep MLP)
//  - blocks [CBLK, +ZBLK):  pure float4 nontemporal store sweep zeroing the
//                           output (replaces hipMemsetAsync, whose rocclr
//                           fill kernel showed 4x write amplification: 524 MB
//                           HBM writes for a 131 MB buffer, 80 us).
// Read and write streams overlap on the HBM bus via different waves.
// ============================================================================
__global__ __launch_bounds__(NT1) void collect_zero_kernel(
    const float* __restrict__ logits, float* __restrict__ out,
    int* __restrict__ cnt_g, uint2* __restrict__ cand_g)
{
  const int bid = blockIdx.x;

  if (bid >= CBLK) {
    // ---- zeroing blocks: pure write stream, full-line coalesced ----
    const int zb = bid - CBLK;
    const f32x4_t z4 = (f32x4_t)0.f;
    f32x4_t* o4 = (f32x4_t*)out;
    const int total4 = (BATCH * VOCAB) / 4;          // 8,192,000
    for (int i = zb * NT1 + (int)threadIdx.x; i < total4; i += ZBLK * NT1)
      __builtin_nontemporal_store(z4, &o4[i]);
    return;
  }

  // ---- collect blocks: read-only loop ----
  const int b = bid >> 3;            // SLICES == 8
  const int s = bid & (SLICES - 1);
  const float4* row4 = (const float4*)(logits + (size_t)b * VOCAB);
  const int per = (VOCAB / 4) / SLICES;   // 4000 float4 per slice
  const int lo = s * per, hi = lo + per;
  int*   cnt  = cnt_g + b;
  uint2* cand = cand_g + (size_t)b * LCAP;

  int i = lo + (int)threadIdx.x;

  // main loop: 4 independent loads issued before any consume
  for (; i + 3 * NT1 < hi; i += 4 * NT1) {
    float4 a = row4[i];
    float4 b4 = row4[i + NT1];
    float4 c = row4[i + 2 * NT1];
    float4 d = row4[i + 3 * NT1];
    if (max4(a)  > TRAW) push4(a,  4u * (unsigned)i,             cnt, cand);
    if (max4(b4) > TRAW) push4(b4, 4u * (unsigned)(i + NT1),     cnt, cand);
    if (max4(c)  > TRAW) push4(c,  4u * (unsigned)(i + 2 * NT1), cnt, cand);
    if (max4(d)  > TRAW) push4(d,  4u * (unsigned)(i + 3 * NT1), cnt, cand);
  }
  // tail
  for (; i < hi; i += NT1) {
    float4 a = row4[i];
    if (max4(a) > TRAW) push4(a, 4u * (unsigned)i, cnt, cand);
  }
}

// ============================================================================
// Kernel 2: per-row selection. 256 blocks x 512 threads. Penalty + temperature
// on ~173 candidates, rank sort (keys unique via idx tie-break -> bijection),
// top-k boundary w/ ties, nucleus cutoff, scatter.
// Self-contained bisection rescan fallback if the candidate set is invalid
// (never for this input distribution).
// ============================================================================
__global__ __launch_bounds__(NT2) void select_kernel(
    const float* __restrict__ logits, const int* __restrict__ prev,
    float* __restrict__ out, const int* __restrict__ cnt_g,
    const uint2* __restrict__ cand_g)
{
  __shared__ unsigned bitmask[BITWORDS];          // 16000 B
  __shared__ unsigned long long keys[LCAP];       //  8192 B
  __shared__ unsigned long long skeys[LCAP];      //  8192 B
  __shared__ float evals[LCAP];                   //  4096 B
  __shared__ int s_cnt, s_good, s_m, s_j;
  __shared__ float s_maxx, s_Z2;

  const int b   = blockIdx.x;
  const int tid = threadIdx.x;
  const float* row  = logits + (size_t)b * VOCAB;
  float*       orow = out    + (size_t)b * VOCAB;

  // ---- seen-token bitmask ----
  for (int i = tid; i < BITWORDS; i += NT2) bitmask[i] = 0u;
  if (tid == 0) s_good = 0;
  __syncthreads();
  for (int i = tid; i < HIST; i += NT2) {
    int t = prev[b * HIST + i];
    atomicOr(&bitmask[t >> 5], 1u << (t & 31));
  }
  __syncthreads();

  // ---- fast path: penalize + temperature the collected candidates ----
  int cnt = cnt_g[b];
  int mn = cnt < LCAP ? cnt : LCAP;
  const uint2* cand = cand_g + (size_t)b * LCAP;
  for (int i = tid; i < mn; i += NT2) {
    uint2 c = cand[i];
    float v = __uint_as_float(c.x);
    unsigned idx = c.y;
    float y = v;
    if ((bitmask[idx >> 5] >> (idx & 31)) & 1u)
      y = (v < 0.0f) ? v * 1.2f : v / 1.2f;        // repetition penalty
    float x = y / 0.6f;                            // temperature (exact IEEE div)
    keys[i] = ((unsigned long long)fkey_of(x) << 32) |
              (unsigned)(~idx);                    // tie-break: smaller idx first
    if (y > TRAW) atomicAdd(&s_good, 1);
  }
  __syncthreads();

  // Valid iff all tokens with y > TRAW were collected AND >= TOPK of them exist
  // (tokens not collected have y <= TRAW, so kth_y > TRAW guarantees coverage).
  if (cnt > LCAP || s_good < TOPK) {
    // ---- fallback: bisection rescan from global memory (rare/never) ----
    float T = TRAW;
    float Tlo = 0.f, Thi = 0.f;
    bool hasLo = false, hasHi = false;
    const float4* row4 = (const float4*)row;
    const int N4 = VOCAB / 4;
    for (int attempt = 0; attempt < 40; ++attempt) {
      __syncthreads();
      if (tid == 0) s_cnt = 0;
      __syncthreads();
      for (int i = tid; i < N4; i += NT2) {
        float4 v4 = row4[i];
        int v0 = i * 4;
        unsigned w  = bitmask[v0 >> 5];
        unsigned sh = v0 & 31;
        float vv[4] = {v4.x, v4.y, v4.z, v4.w};
        #pragma unroll
        for (int l = 0; l < 4; ++l) {
          float v = vv[l];
          float y = v;
          if ((w >> (sh + l)) & 1u)
            y = (v < 0.0f) ? v * 1.2f : v / 1.2f;
          if (y > T) {
            int pos = atomicAdd(&s_cnt, 1);
            if (pos < LCAP) {
              unsigned k = fkey_of(y / 0.6f);
              keys[pos] = ((unsigned long long)k << 32) |
                          (unsigned)(~(unsigned)(v0 + l));
            }
          }
        }
      }
      __syncthreads();
      cnt = s_cnt;
      if (cnt >= TOPK && cnt <= LCAP) break;
      if (cnt < TOPK) { Thi = T; hasHi = true; T = hasLo ? 0.5f * (T + Tlo) : T - 1.0f; }
      else            { Tlo = T; hasLo = true; T = hasHi ? 0.5f * (T + Thi) : T + 1.0f; }
    }
    if (cnt > LCAP) cnt = LCAP;
  }

  // ---- rank sort: keys unique (idx tie-break) => ranks are a bijection ----
  // cnt ~173: each thread ranks <=1 key with an LDS-broadcast inner loop.
  for (int i = tid; i < cnt; i += NT2) {
    unsigned long long a = keys[i];
    int r = 0;
    for (int j = 0; j < cnt; ++j) r += (keys[j] > a);
    skeys[r] = a;
  }
  __syncthreads();

  // ---- top-k boundary (keep ties at kth) + max ----
  if (tid == 0) {
    int kk = (cnt < TOPK) ? cnt : TOPK;
    unsigned kth = (unsigned)(skeys[kk - 1] >> 32);
    int m = kk;
    while (m < cnt && (unsigned)(skeys[m] >> 32) == kth) m++;
    s_m = m;
    s_maxx = f_of_key((unsigned)(skeys[0] >> 32));
  }
  __syncthreads();
  int m = s_m;
  float maxx = s_maxx;
  for (int i = tid; i < m; i += NT2)
    evals[i] = expf(f_of_key((unsigned)(skeys[i] >> 32)) - maxx);
  __syncthreads();

  // ---- nucleus cutoff: keep token i iff i==0 or cumsum(p[0..i-1]) <= 0.9 ----
  if (tid == 0) {
    float Z = 0.f;
    for (int i = 0; i < m; ++i) Z += evals[i];
    float cum = 0.f;
    int j = 0;
    for (int i = 0; i < m; ++i) {
      if (i > 0 && cum > 0.9f) break;
      cum += evals[i] / Z;
      j = i + 1;
    }
    float Z2 = 0.f;
    for (int i = 0; i < j; ++i) Z2 += evals[i];
    s_j = j; s_Z2 = Z2;
  }
  __syncthreads();

  // ---- scatter final probs (row already zeroed) ----
  int j = s_j;
  float Z2 = s_Z2;
  for (int i = tid; i < j; i += NT2) {
    int idx = (int)(~(unsigned)(skeys[i] & 0xFFFFFFFFull));
    orow[idx] = evals[i] / Z2;
  }
}

// ============================================================================
// Monolithic fallback (round-0 kernel) — used only if ws_size is too small
// for the two-kernel workspace.
// ============================================================================
__global__ __launch_bounds__(NTHREADS) void sample_head_kernel(
    const float* __restrict__ logits, const int* __restrict__ prev,
    float* __restrict__ out)
{
  __shared__ unsigned bitmask[BITWORDS];
  __shared__ unsigned long long keys[CAP];
  __shared__ float evals[CAP];
  __shared__ int s_count;
  __shared__ int s_m, s_j;
  __shared__ float s_maxx, s_Z2;

  const int b   = blockIdx.x;
  const int tid = threadIdx.x;
  const float* row  = logits + (size_t)b * VOCAB;
  float*       orow = out    + (size_t)b * VOCAB;

  for (int i = tid; i < BITWORDS; i += NTHREADS) bitmask[i] = 0u;
  __syncthreads();
  for (int i = tid; i < HIST; i += NTHREADS) {
    int t = prev[b * HIST + i];
    atomicOr(&bitmask[t >> 5], 1u << (t & 31));
  }
  __syncthreads();

  float T = 3.0f;
  float Tlo = 0.f, Thi = 0.f;
  bool hasLo = false, hasHi = false;
  int cnt = 0;

  const float4* row4  = (const float4*)row;
  float4*       orow4 = (float4*)orow;
  const int N4 = VOCAB / 4;

  for (int attempt = 0; attempt < 40; ++attempt) {
    __syncthreads();
    if (tid == 0) s_count = 0;
    __syncthreads();

    for (int i = tid; i < N4; i += NTHREADS) {
      float4 v4 = row4[i];
      if (attempt == 0) orow4[i] = make_float4(0.f, 0.f, 0.f, 0.f);
      int v0 = i * 4;
      unsigned w  = bitmask[v0 >> 5];
      unsigned sh = v0 & 31;
      float vv[4] = {v4.x, v4.y, v4.z, v4.w};
      #pragma unroll
      for (int l = 0; l < 4; ++l) {
        float v = vv[l];
        float y = v;
        if ((w >> (sh + l)) & 1u)
          y = (v < 0.0f) ? v * 1.2f : v / 1.2f;
        if (y > T) {
          float x = y / 0.6f;
          int pos = atomicAdd(&s_count, 1);
          if (pos < CAP) {
            unsigned k = fkey_of(x);
            keys[pos] = ((unsigned long long)k << 32) |
                        (unsigned)(~(unsigned)(v0 + l));
          }
        }
      }
    }
    __syncthreads();
    cnt = s_count;
    if (cnt >= TOPK && cnt <= CAP) break;
    if (cnt < TOPK) { Thi = T; hasHi = true; T = hasLo ? 0.5f * (T + Tlo) : T - 1.0f; }
    else            { Tlo = T; hasLo = true; T = hasHi ? 0.5f * (T + Thi) : T + 1.0f; }
  }
  if (cnt > CAP) cnt = CAP;

  int n = 64;
  while (n < cnt) n <<= 1;
  for (int i = cnt + tid; i < n; i += NTHREADS) keys[i] = 0ull;
  __syncthreads();
  for (int k = 2; k <= n; k <<= 1) {
    for (int j = k >> 1; j > 0; j >>= 1) {
      for (int i = tid; i < n; i += NTHREADS) {
        int l = i ^ j;
        if (l > i) {
          unsigned long long a = keys[i], c = keys[l];
          bool up = (i & k) == 0;
          if (up ? (a < c) : (a > c)) { keys[i] = c; keys[l] = a; }
        }
      }
      __syncthreads();
    }
  }

  if (tid == 0) {
    int kk = (cnt < TOPK) ? cnt : TOPK;
    unsigned kth = (unsigned)(keys[kk - 1] >> 32);
    int m = kk;
    while (m < cnt && (unsigned)(keys[m] >> 32) == kth) m++;
    s_m = m;
    s_maxx = f_of_key((unsigned)(keys[0] >> 32));
  }
  __syncthreads();
  int m = s_m;
  float maxx = s_maxx;
  for (int i = tid; i < m; i += NTHREADS)
    evals[i] = expf(f_of_key((unsigned)(keys[i] >> 32)) - maxx);
  __syncthreads();

  if (tid == 0) {
    float Z = 0.f;
    for (int i = 0; i < m; ++i) Z += evals[i];
    float cum = 0.f;
    int j = 0;
    for (int i = 0; i < m; ++i) {
      if (i > 0 && cum > 0.9f) break;
      cum += evals[i] / Z;
      j = i + 1;
    }
    float Z2 = 0.f;
    for (int i = 0; i < j; ++i) Z2 += evals[i];
    s_j = j; s_Z2 = Z2;
  }
  __syncthreads();

  int j = s_j;
  float Z2 = s_Z2;
  for (int i = tid; i < j; i += NTHREADS) {
    int idx = (int)(~(unsigned)(keys[i] & 0xFFFFFFFFull));
    orow[idx] = evals[i] / Z2;
  }
}

extern "C" void kernel_launch(void* const* d_in, const int* in_sizes, int n_in,
                              void* d_out, int out_size, void* d_ws, size_t ws_size,
                              hipStream_t stream) {
  const float* logits = (const float*)d_in[0];
  const int*   prev   = (const int*)d_in[1];
  float*       out    = (float*)d_out;

  const size_t cnt_bytes  = (size_t)BATCH * sizeof(int);
  const size_t cand_off   = 1024;  // 8B-aligned, past counters
  const size_t need       = cand_off + (size_t)BATCH * LCAP * sizeof(uint2);

  if (d_ws != nullptr && ws_size >= need) {
    int*   cnt_g  = (int*)d_ws;
    uint2* cand_g = (uint2*)((char*)d_ws + cand_off);
    hipMemsetAsync(d_ws, 0, cnt_bytes, stream);
    hipLaunchKernelGGL(collect_zero_kernel, dim3(CBLK + ZBLK), dim3(NT1),
                       0, stream, logits, out, cnt_g, cand_g);
    hipLaunchKernelGGL(select_kernel, dim3(BATCH), dim3(NT2),
                       0, stream, logits, prev, out, cnt_g, cand_g);
  } else {
    hipLaunchKernelGGL(sample_head_kernel, dim3(BATCH), dim3(NTHREADS),
                       0, stream, logits, prev, out);
  }
}